// Round 14
// baseline (3532.928 us; speedup 1.0000x reference)
//
#include <hip/hip_runtime.h>

typedef __bf16 bf16x8 __attribute__((ext_vector_type(8)));
typedef float f32x4 __attribute__((ext_vector_type(4)));

#define SCALEF 0.08838834764831843f
#define FL_SIG 2

__device__ __forceinline__ float bf2f(short u) {
    unsigned int x = ((unsigned int)(unsigned short)u) << 16;
    return __builtin_bit_cast(float, x);
}
__device__ __forceinline__ short f2bf(float f) {
    unsigned int x = __builtin_bit_cast(unsigned int, f);
    unsigned int r = (x + 0x7FFFu + ((x >> 16) & 1u)) >> 16;
    return (short)(unsigned short)r;
}
__device__ __forceinline__ unsigned int pkbf(float lo, float hi) {
    return ((unsigned int)(unsigned short)f2bf(lo)) | (((unsigned int)(unsigned short)f2bf(hi)) << 16);
}
// packed bf16 relu in ONE VALU op: signed-i16 max with 0 clamps any sign-set half
// (negative bf16, incl -0.0) to +0.0 and keeps positives. Constant 0 is op_sel_hi-safe
// (both halves of the inline constant are 0) — unlike round-13's `15` shift constant.
__device__ __forceinline__ unsigned int relu_pk(unsigned int p) {
    unsigned int r;
    asm("v_pk_max_i16 %0, %1, 0" : "=v"(r) : "v"(p));
    return r;
}
__device__ __forceinline__ void gload16(const void* g, void* l) {
    __builtin_amdgcn_global_load_lds(
        (const __attribute__((address_space(1))) unsigned int*)g,
        (__attribute__((address_space(3))) unsigned int*)l, 16, 0, 0);
}

struct GP {
    const short* A1; const short* A2; const short* WT;
    const float* bias; const float* rmask; void* C;
    int k2s, lda, M, N, K, ldc, flags;
};

// ---------------- batched-pair bf16 GEMM (2-phase, proven structure; 5 blocks/CU) ----------------
template<int RELU, int CF32>
__global__ __launch_bounds__(256, 5) void gemm2_k(GP p0, GP p1)
{
    GP p = (blockIdx.z == 0) ? p0 : p1;
    const int nbx = p.N >> 7;
    const int nby = p.M >> 7;
    if ((int)blockIdx.y >= nby) return;          // uniform early-exit (before any barrier)

    __shared__ short lA[128 * 64];
    __shared__ short lB[128 * 64];
    const int tid = threadIdx.x;
    const int lane = tid & 63;
    const int wave = tid >> 6;
    const int wr = wave >> 1, wc = wave & 1;
    const int q16 = lane & 15, gk = lane >> 4;

    const int nwg = nbx * nby;
    int orig = blockIdx.y * nbx + blockIdx.x;
    int qq = nwg >> 3, rr = nwg & 7;
    int xcd = orig & 7, idx = orig >> 3;
    int swz = (xcd < rr ? xcd * (qq + 1) : rr * (qq + 1) + (xcd - rr) * qq) + idx;
    const int bn = (swz % nbx) * 128;
    const int bm = (swz / nbx) * 128;

    const int srow = lane >> 3;
    const int scol = ((lane & 7) ^ srow) * 8;

    f32x4 acc[4][4];
#pragma unroll
    for (int i = 0; i < 4; ++i)
#pragma unroll
        for (int j = 0; j < 4; ++j) acc[i][j] = (f32x4){0.f, 0.f, 0.f, 0.f};

    for (int k0 = 0; k0 < p.K; k0 += 64) {
        const short* Asrc = p.A1; int kc = k0;
        if (p.A2 != nullptr && k0 >= p.k2s) { Asrc = p.A2; kc = k0 - p.k2s; }
#pragma unroll
        for (int i = 0; i < 4; ++i) {
            int chunk = wave * 4 + i;
            int row = chunk * 8 + srow;
            gload16(Asrc + (size_t)(bm + row) * p.lda + kc + scol, lA + chunk * 512);
            gload16(p.WT + (size_t)(bn + row) * p.K + k0 + scol, lB + chunk * 512);
        }
        __syncthreads();
#pragma unroll
        for (int kk = 0; kk < 2; ++kk) {
            bf16x8 af[4], bfr[4];
#pragma unroll
            for (int i = 0; i < 4; ++i) {
                int row = wr * 64 + i * 16 + q16;
                int off = (row * 128 + kk * 64 + gk * 16) ^ ((row & 7) << 4);
                af[i] = *(const bf16x8*)((const char*)lA + off);
                if (RELU) {
                    union { bf16x8 v; unsigned int w[4]; } u;
                    u.v = af[i];
#pragma unroll
                    for (int t = 0; t < 4; ++t) u.w[t] = relu_pk(u.w[t]);
                    af[i] = u.v;
                }
            }
#pragma unroll
            for (int j = 0; j < 4; ++j) {
                int row = wc * 64 + j * 16 + q16;
                int off = (row * 128 + kk * 64 + gk * 16) ^ ((row & 7) << 4);
                bfr[j] = *(const bf16x8*)((const char*)lB + off);
            }
#pragma unroll
            for (int i = 0; i < 4; ++i)
#pragma unroll
                for (int j = 0; j < 4; ++j)
                    acc[i][j] = __builtin_amdgcn_mfma_f32_16x16x32_bf16(af[i], bfr[j], acc[i][j], 0, 0, 0);
        }
        __syncthreads();
    }
    const bool sig = (p.flags & FL_SIG) != 0;
#pragma unroll
    for (int i = 0; i < 4; ++i) {
#pragma unroll
        for (int j = 0; j < 4; ++j) {
            int col = bn + wc * 64 + j * 16 + q16;
            float bv = p.bias[col];
#pragma unroll
            for (int r = 0; r < 4; ++r) {
                int row = bm + wr * 64 + i * 16 + gk * 4 + r;
                float v = acc[i][j][r] + bv;
                if (sig) v = 1.f + 1.f / (1.f + __expf(-v));
                if (p.rmask) v *= p.rmask[row];
                if (CF32) ((float*)p.C)[(size_t)row * p.ldc + col] = v;
                else      ((short*)p.C)[(size_t)row * p.ldc + col] = f2bf(v);
            }
        }
    }
}

// ---------------- batched-pair MFMA attention, per-z compile-time KT ----------------
struct AP {
    const short* q; const short* kv; const float* mask; const short* gate;
    const short* add; short* out; int Nq, Nk;
};

template<int KT>
__device__ __forceinline__ void attn_body(const AP& a, short* sK, short* sVT, float* sMask)
{
    constexpr int KT2 = (KT + 1) / 2;
    constexpr int KV = KT2 * 32;
    constexpr int VROWB = KV * 2;
    const int Nq = a.Nq, Nk = a.Nk;
    const int tid = threadIdx.x;
    const int h = blockIdx.x, b = blockIdx.y;
    const int lane = tid & 63, w = tid >> 6;
    const int g = lane >> 4, q16 = lane & 15;

    union U8 { uint4 u4; short s[8]; };

    for (int u = tid; u < Nk * 16; u += 256) {
        int k = u >> 4, seg = u & 15;
        U8 t; t.u4 = *(const uint4*)(a.kv + (size_t)(b * Nk + k) * 3072 + h * 128 + seg * 8);
        if (a.gate) {
            const short* gp = a.gate + b * 1024 + h * 128 + seg * 8;
#pragma unroll
            for (int j = 0; j < 8; ++j) {
                float gv = bf2f(gp[j]);
                t.s[j] = f2bf(bf2f(t.s[j]) * gv * gv);
            }
        }
        int off = (k * 256 + seg * 16) ^ ((k & 7) << 4);
        *(uint4*)((char*)sK + off) = t.u4;
    }
    for (int u = tid; u < Nk * 16; u += 256) {
        int k = u >> 4, seg = u & 15;
        U8 t; t.u4 = *(const uint4*)(a.kv + (size_t)(b * Nk + k) * 3072 + 2048 + h * 128 + seg * 8);
#pragma unroll
        for (int j = 0; j < 8; ++j) {
            int d = seg * 8 + j;
            int off = (d * VROWB + ((k >> 3) << 4) + (k & 7) * 2) ^ ((d & 7) << 4);
            *(short*)((char*)sVT + off) = t.s[j];
        }
    }
    for (int u = tid; u < (KV - Nk) * 128; u += 256) {
        int k = Nk + (u >> 7), d = u & 127;
        int off = (d * VROWB + ((k >> 3) << 4) + (k & 7) * 2) ^ ((d & 7) << 4);
        *(short*)((char*)sVT + off) = 0;
    }
    for (int u = tid; u < KV; u += 256)
        sMask[u] = (u < Nk) ? a.mask[b * Nk + u] : 0.f;
    __syncthreads();

    const int QT = (Nq + 15) >> 4;
    for (int qt = w; qt < QT; qt += 4) {
        int qrow = qt * 16 + q16; if (qrow >= Nq) qrow = Nq - 1;
        const short* qp = a.q + (size_t)(b * Nq + qrow) * 3072 + 1024 + h * 128 + g * 8;
        bf16x8 qf[4];
#pragma unroll
        for (int ks = 0; ks < 4; ++ks)
            qf[ks] = *(const bf16x8*)(qp + ks * 32);

        f32x4 accs[KT];
#pragma unroll
        for (int kt = 0; kt < KT; ++kt) accs[kt] = (f32x4){0.f, 0.f, 0.f, 0.f};
#pragma unroll
        for (int kt = 0; kt < KT; ++kt) {
            int krow = kt * 16 + q16;
#pragma unroll
            for (int ks = 0; ks < 4; ++ks) {
                bf16x8 kf = *(const bf16x8*)((char*)sK +
                    ((krow * 256 + ks * 64 + g * 16) ^ ((krow & 7) << 4)));
                accs[kt] = __builtin_amdgcn_mfma_f32_16x16x32_bf16(kf, qf[ks], accs[kt], 0, 0, 0);
            }
        }
        float pv[KT][4];
        float mx = -__builtin_inff();
#pragma unroll
        for (int kt = 0; kt < KT; ++kt)
#pragma unroll
            for (int r = 0; r < 4; ++r) {
                int k = kt * 16 + g * 4 + r;
                float s = (sMask[k] > 0.f) ? accs[kt][r] * SCALEF : -__builtin_inff();
                pv[kt][r] = s;
                mx = fmaxf(mx, s);
            }
        mx = fmaxf(mx, __shfl_xor(mx, 16, 64));
        mx = fmaxf(mx, __shfl_xor(mx, 32, 64));
        float sum = 0.f;
#pragma unroll
        for (int kt = 0; kt < KT; ++kt)
#pragma unroll
            for (int r = 0; r < 4; ++r) {
                float pp = __expf(pv[kt][r] - mx);
                pv[kt][r] = pp;
                sum += pp;
            }
        sum += __shfl_xor(sum, 16, 64);
        sum += __shfl_xor(sum, 32, 64);
        float rden = 1.f / sum;

        unsigned int wA[KT2 * 2], wB[KT2 * 2];
#pragma unroll
        for (int t = 0; t < KT2 * 2; ++t) {
            if (t < KT) { wA[t] = pkbf(pv[t][0], pv[t][1]); wB[t] = pkbf(pv[t][2], pv[t][3]); }
            else { wA[t] = 0u; wB[t] = 0u; }
        }
        f32x4 acco[8];
#pragma unroll
        for (int dt = 0; dt < 8; ++dt) acco[dt] = (f32x4){0.f, 0.f, 0.f, 0.f};
        const int srcA = (((g & 1) * 2) * 16 + q16) * 4;
        const int srcB = (((g & 1) * 2 + 1) * 16 + q16) * 4;
        const bool hi = g >= 2;
#pragma unroll
        for (int kt2 = 0; kt2 < KT2; ++kt2) {
            int a0_ = __builtin_amdgcn_ds_bpermute(srcA, (int)wA[2 * kt2]);
            int a1_ = __builtin_amdgcn_ds_bpermute(srcA, (int)wA[2 * kt2 + 1]);
            int b0_ = __builtin_amdgcn_ds_bpermute(srcA, (int)wB[2 * kt2]);
            int b1_ = __builtin_amdgcn_ds_bpermute(srcA, (int)wB[2 * kt2 + 1]);
            int c0_ = __builtin_amdgcn_ds_bpermute(srcB, (int)wA[2 * kt2]);
            int c1_ = __builtin_amdgcn_ds_bpermute(srcB, (int)wA[2 * kt2 + 1]);
            int d0_ = __builtin_amdgcn_ds_bpermute(srcB, (int)wB[2 * kt2]);
            int d1_ = __builtin_amdgcn_ds_bpermute(srcB, (int)wB[2 * kt2 + 1]);
            union { int wd[4]; bf16x8 v; } pf;
            pf.wd[0] = hi ? a1_ : a0_;
            pf.wd[1] = hi ? b1_ : b0_;
            pf.wd[2] = hi ? c1_ : c0_;
            pf.wd[3] = hi ? d1_ : d0_;
#pragma unroll
            for (int dt = 0; dt < 8; ++dt) {
                int drow = dt * 16 + q16;
                bf16x8 vf = *(const bf16x8*)((char*)sVT +
                    ((drow * VROWB + kt2 * 64 + g * 16) ^ ((drow & 7) << 4)));
                acco[dt] = __builtin_amdgcn_mfma_f32_16x16x32_bf16(pf.v, vf, acco[dt], 0, 0, 0);
            }
        }
        float rd[4];
#pragma unroll
        for (int r = 0; r < 4; ++r) {
            int rv = __builtin_amdgcn_ds_bpermute((g * 4 + r) * 4, __builtin_bit_cast(int, rden));
            rd[r] = __builtin_bit_cast(float, rv);
        }
#pragma unroll
        for (int dt = 0; dt < 8; ++dt)
#pragma unroll
            for (int r = 0; r < 4; ++r) {
                int q = qt * 16 + g * 4 + r;
                if (q < Nq) {
                    size_t oidx = (size_t)(b * Nq + q) * 1024 + h * 128 + dt * 16 + q16;
                    float val = acco[dt][r] * rd[r];
                    if (a.add) val += bf2f(a.add[oidx]);
                    a.out[oidx] = f2bf(val);
                }
            }
    }
}

template<int KT0, int KT1>
__global__ __launch_bounds__(256, 2) void attn2_mfma(AP a0, AP a1)
{
    __shared__ short sK[112 * 128];
    __shared__ short sVT[128 * 128];
    __shared__ float sMask[128];
    if (blockIdx.z == 0) attn_body<KT0>(a0, sK, sVT, sMask);
    else                 attn_body<KT1>(a1, sK, sVT, sMask);
}

// ---------------- fused helpers ----------------
struct TP { const float* W; short* WT; int K, N, nblk; };
struct TPack { TP t[12]; };

__global__ void transpose12_k(TPack pk) {
    __shared__ short tile[32][33];
    int bid = blockIdx.x;
    int pi = 0;
    while (bid >= pk.t[pi].nblk) { bid -= pk.t[pi].nblk; ++pi; }
    const float* W = pk.t[pi].W;
    short* WT = pk.t[pi].WT;
    int K = pk.t[pi].K, N = pk.t[pi].N;
    int nbx = N >> 5;
    int nb = (bid % nbx) * 32, kb = (bid / nbx) * 32;
    int tx = threadIdx.x & 31, ty = threadIdx.x >> 5;
    for (int i = ty; i < 32; i += 8)
        tile[i][tx] = f2bf(W[(size_t)(kb + i) * N + nb + tx]);
    __syncthreads();
    for (int i = ty; i < 32; i += 8)
        WT[(size_t)(nb + i) * K + kb + tx] = tile[tx][i];
}

__global__ void cvt2_bf(const float* __restrict__ a, short* __restrict__ oa, int na8,
                        const float* __restrict__ b, short* __restrict__ ob, int nb8) {
    int i = blockIdx.x * 256 + threadIdx.x;
    const float* src; short* dst; int loc;
    if (i < na8) { src = a; dst = oa; loc = i; }
    else if (i < na8 + nb8) { src = b; dst = ob; loc = i - na8; }
    else return;
    const float4* p = (const float4*)(src + (size_t)loc * 8);
    float4 x = p[0], y = p[1];
    uint4 val;
    val.x = pkbf(x.x, x.y); val.y = pkbf(x.z, x.w);
    val.z = pkbf(y.x, y.y); val.w = pkbf(y.z, y.w);
    *(uint4*)(dst + (size_t)loc * 8) = val;
}

__global__ void mean2_k(const short* __restrict__ Xv, const float* __restrict__ mv, short* __restrict__ ov_,
                        const short* __restrict__ Xt, const float* __restrict__ mt, short* __restrict__ ot_) {
    int idx = blockIdx.x * 256 + threadIdx.x;
    const short* X; const float* mk; short* o; int N; int loc;
    if (idx < 131072) { X = Xv; mk = mv; o = ov_; N = 100; loc = idx; }
    else { X = Xt; mk = mt; o = ot_; N = 36; loc = idx - 131072; }
    int b = loc >> 10, d = loc & 1023;
    float s = 0.f, c = 0.f;
    for (int n = 0; n < N; ++n) {
        float m = mk[b * N + n];
        s += bf2f(X[(size_t)(b * N + n) * 1024 + d]) * m;
        c += m;
    }
    o[loc] = f2bf(s / c);
}

// ---------------- orchestration ----------------
extern "C" void kernel_launch(void* const* d_in, const int* in_sizes, int n_in,
                              void* d_out, int out_size, void* d_ws, size_t ws_size,
                              hipStream_t stream)
{
    const float* v_in  = (const float*)d_in[0];
    const float* t_in  = (const float*)d_in[1];
    const float* vm    = (const float*)d_in[2];
    const float* tm    = (const float*)d_in[3];
    const float* vlin_w = (const float*)d_in[4];  const float* vlin_b = (const float*)d_in[5];
    const float* tlin_w = (const float*)d_in[6];  const float* tlin_b = (const float*)d_in[7];
    const float* iv_w  = (const float*)d_in[8];   const float* iv_b  = (const float*)d_in[9];
    const float* it_w  = (const float*)d_in[10];  const float* it_b  = (const float*)d_in[11];
    const float* ivo_w = (const float*)d_in[12];  const float* ivo_b = (const float*)d_in[13];
    const float* ito_w = (const float*)d_in[14];  const float* ito_b = (const float*)d_in[15];
    const float* gv_w  = (const float*)d_in[16];  const float* gv_b  = (const float*)d_in[17];
    const float* gt_w  = (const float*)d_in[18];  const float* gt_b  = (const float*)d_in[19];
    const float* av_w  = (const float*)d_in[20];  const float* av_b  = (const float*)d_in[21];
    const float* at_w  = (const float*)d_in[22];  const float* at_b  = (const float*)d_in[23];
    const float* avo_w = (const float*)d_in[24];  const float* avo_b = (const float*)d_in[25];
    const float* ato_w = (const float*)d_in[26];  const float* ato_b = (const float*)d_in[27];

    short* ws = (short*)d_ws;
    const size_t WTvlin = 0;
    const size_t WTtlin = 2097152;
    const size_t WTiv   = 3145728;
    const size_t WTit   = 6291456;
    const size_t WTivo  = 9437184;
    const size_t WTito  = 11534336;
    const size_t WTgv   = 13631488;
    const size_t WTgt   = 14680064;
    const size_t WTav   = 15728640;
    const size_t WTat   = 18874368;
    const size_t WTavo  = 22020096;
    const size_t WTato  = 23068672;
    const size_t V_A    = 24117248;
    const size_t V_B    = 37224448;
    const size_t T_A    = 50331648;
    const size_t T_B    = 55050240;
    const size_t VT     = 59768832;
    const size_t TT     = 99090432;
    const size_t V_UP   = 113246208;
    const size_t T_UP   = 126353408;
    const size_t VMEAN  = 131072000;
    const size_t TMEAN  = 131203072;
    const size_t GATEV  = 131334144;
    const size_t GATET  = 131465216;
    const size_t TOTAL  = 131596288;
    if (ws_size < TOTAL * 2ull) return;

    short* v_a = ws + V_A; short* v_b = ws + V_B;
    short* t_a = ws + T_A; short* t_b = ws + T_B;
    short* vt = ws + VT;   short* tt = ws + TT;
    short* v_up = ws + V_UP; short* t_up = ws + T_UP;
    short* vmean = ws + VMEAN; short* tmean = ws + TMEAN;
    short* gateV = ws + GATEV; short* gateT = ws + GATET;
    float* ov = (float*)d_out;
    float* ot = ov + 13107200;

    {
        TPack pk;
        auto set = [&](int i, const float* W, size_t off, int K, int N) {
            pk.t[i] = TP{W, ws + off, K, N, (N / 32) * (K / 32)};
        };
        set(0, vlin_w, WTvlin, 2048, 1024);  set(1, tlin_w, WTtlin, 1024, 1024);
        set(2, iv_w, WTiv, 1024, 3072);      set(3, it_w, WTit, 1024, 3072);
        set(4, ivo_w, WTivo, 2048, 1024);    set(5, ito_w, WTito, 2048, 1024);
        set(6, gv_w, WTgv, 1024, 1024);      set(7, gt_w, WTgt, 1024, 1024);
        set(8, av_w, WTav, 1024, 3072);      set(9, at_w, WTat, 1024, 3072);
        set(10, avo_w, WTavo, 1024, 1024);   set(11, ato_w, WTato, 1024, 1024);
        int total = 0;
        for (int i = 0; i < 12; ++i) total += pk.t[i].nblk;
        transpose12_k<<<total, 256, 0, stream>>>(pk);
    }

    auto GPm = [&](const short* A1, const short* A2, int k2s, int lda, size_t WToff,
                   const float* bp, const float* rm, void* Cp, int M, int N, int K, int flags) {
        return GP{A1, A2, ws + WToff, bp, rm, Cp, k2s, lda, M, N, K, N, flags};
    };
    auto APm = [&](const short* q, const short* kv, const float* mk, const short* gt,
                   const short* adds, short* o, int Nq, int Nk) {
        return AP{q, kv, mk, gt, adds, o, Nq, Nk};
    };

    {
        short* v_cv = ws + VT;
        short* t_cv = ws + TT;
        int na8 = 12800 * 2048 / 8, nb8 = 4608 * 1024 / 8;
        cvt2_bf<<<(na8 + nb8 + 255) / 256, 256, 0, stream>>>(v_in, v_cv, na8, t_in, t_cv, nb8);
        gemm2_k<0, 0><<<dim3(8, 100, 2), 256, 0, stream>>>(
            GPm(v_cv, nullptr, 0, 2048, WTvlin, vlin_b, vm, v_a, 12800, 1024, 2048, 0),
            GPm(t_cv, nullptr, 0, 1024, WTtlin, tlin_b, tm, t_a, 4608, 1024, 1024, 0));
    }

    for (int ib = 0; ib < 2; ++ib) {
        // ---- InterModalityUpdate ----
        gemm2_k<1, 0><<<dim3(24, 100, 2), 256, 0, stream>>>(
            GPm(v_a, nullptr, 0, 1024, WTiv, iv_b, nullptr, vt, 12800, 3072, 1024, 0),
            GPm(t_a, nullptr, 0, 1024, WTit, it_b, nullptr, tt, 4608, 3072, 1024, 0));
        attn2_mfma<3, 7><<<dim3(8, 128, 2), 256, 0, stream>>>(
            APm(vt, tt, tm, nullptr, nullptr, v_up, 100, 36),     // t2v (Nk=36)
            APm(tt, vt, vm, nullptr, nullptr, t_up, 36, 100));    // v2t (Nk=100)
        gemm2_k<0, 0><<<dim3(8, 100, 2), 256, 0, stream>>>(
            GPm(v_a, v_up, 1024, 1024, WTivo, ivo_b, nullptr, v_b, 12800, 1024, 2048, 0),
            GPm(t_a, t_up, 1024, 1024, WTito, ito_b, nullptr, t_b, 4608, 1024, 2048, 0));
        // ---- DyIntraModalityUpdate ----
        mean2_k<<<1024, 256, 0, stream>>>(v_b, vm, vmean, t_b, tm, tmean);
        gemm2_k<1, 0><<<dim3(8, 1, 2), 256, 0, stream>>>(
            GPm(vmean, nullptr, 0, 1024, WTgv, gv_b, nullptr, gateT, 128, 1024, 1024, FL_SIG),
            GPm(tmean, nullptr, 0, 1024, WTgt, gt_b, nullptr, gateV, 128, 1024, 1024, FL_SIG));
        gemm2_k<1, 0><<<dim3(24, 100, 2), 256, 0, stream>>>(
            GPm(v_b, nullptr, 0, 1024, WTav, av_b, vm, vt, 12800, 3072, 1024, 0),
            GPm(t_b, nullptr, 0, 1024, WTat, at_b, tm, tt, 4608, 3072, 1024, 0));
        attn2_mfma<7, 3><<<dim3(8, 128, 2), 256, 0, stream>>>(
            APm(vt, vt, vm, gateV, v_b, v_up, 100, 100),          // v2v (+residual)
            APm(tt, tt, tm, gateT, t_b, t_up, 36, 36));           // t2t (+residual)
        if (ib == 1) {
            gemm2_k<0, 1><<<dim3(8, 100, 2), 256, 0, stream>>>(
                GPm(v_up, nullptr, 0, 1024, WTavo, avo_b, nullptr, ov, 12800, 1024, 1024, 0),
                GPm(t_up, nullptr, 0, 1024, WTato, ato_b, nullptr, ot, 4608, 1024, 1024, 0));
        } else {
            gemm2_k<0, 0><<<dim3(8, 100, 2), 256, 0, stream>>>(
                GPm(v_up, nullptr, 0, 1024, WTavo, avo_b, vm, v_a, 12800, 1024, 1024, 0),
                GPm(t_up, nullptr, 0, 1024, WTato, ato_b, tm, t_a, 4608, 1024, 1024, 0));
        }
    }
}

// Round 15
// 1572.619 us; speedup vs baseline: 2.2465x; 2.2465x over previous
//
#include <hip/hip_runtime.h>

typedef __bf16 bf16x8 __attribute__((ext_vector_type(8)));
typedef float f32x4 __attribute__((ext_vector_type(4)));

#define SCALEF 0.08838834764831843f
#define FL_SIG 2

__device__ __forceinline__ float bf2f(short u) {
    unsigned int x = ((unsigned int)(unsigned short)u) << 16;
    return __builtin_bit_cast(float, x);
}
__device__ __forceinline__ short f2bf(float f) {
    unsigned int x = __builtin_bit_cast(unsigned int, f);
    unsigned int r = (x + 0x7FFFu + ((x >> 16) & 1u)) >> 16;
    return (short)(unsigned short)r;
}
__device__ __forceinline__ unsigned int pkbf(float lo, float hi) {
    return ((unsigned int)(unsigned short)f2bf(lo)) | (((unsigned int)(unsigned short)f2bf(hi)) << 16);
}
// packed bf16 relu in ONE VALU op (verified r14): signed-i16 max with 0 clamps sign-set
// halves (neg bf16, incl -0.0) to +0.0, keeps positives. Constant 0 is op_sel_hi-safe.
__device__ __forceinline__ unsigned int relu_pk(unsigned int p) {
    unsigned int r;
    asm("v_pk_max_i16 %0, %1, 0" : "=v"(r) : "v"(p));
    return r;
}
__device__ __forceinline__ void gload16(const void* g, void* l) {
    __builtin_amdgcn_global_load_lds(
        (const __attribute__((address_space(1))) unsigned int*)g,
        (__attribute__((address_space(3))) unsigned int*)l, 16, 0, 0);
}

struct GP {
    const short* A1; const short* A2; const short* WT;
    const float* bias; const float* rmask; void* C;
    int k2s, lda, M, N, K, ldc, flags;
};

// ---------------- batched-pair bf16 GEMM (2-phase, proven structure; 4 blocks/CU) ----------------
// NOTE (r14 lesson): bounds (256,5) capped VGPR at 48 < 64-reg accumulator -> scratch spill,
// FETCH 3x, 2.3x slower. (256,4) gives VGPR 64, zero spill — do not raise.
template<int RELU, int CF32>
__global__ __launch_bounds__(256, 4) void gemm2_k(GP p0, GP p1)
{
    GP p = (blockIdx.z == 0) ? p0 : p1;
    const int nbx = p.N >> 7;
    const int nby = p.M >> 7;
    if ((int)blockIdx.y >= nby) return;          // uniform early-exit (before any barrier)

    __shared__ short lA[128 * 64];
    __shared__ short lB[128 * 64];
    const int tid = threadIdx.x;
    const int lane = tid & 63;
    const int wave = tid >> 6;
    const int wr = wave >> 1, wc = wave & 1;
    const int q16 = lane & 15, gk = lane >> 4;

    const int nwg = nbx * nby;
    int orig = blockIdx.y * nbx + blockIdx.x;
    int qq = nwg >> 3, rr = nwg & 7;
    int xcd = orig & 7, idx = orig >> 3;
    int swz = (xcd < rr ? xcd * (qq + 1) : rr * (qq + 1) + (xcd - rr) * qq) + idx;
    const int bn = (swz % nbx) * 128;
    const int bm = (swz / nbx) * 128;

    const int srow = lane >> 3;
    const int scol = ((lane & 7) ^ srow) * 8;

    f32x4 acc[4][4];
#pragma unroll
    for (int i = 0; i < 4; ++i)
#pragma unroll
        for (int j = 0; j < 4; ++j) acc[i][j] = (f32x4){0.f, 0.f, 0.f, 0.f};

    for (int k0 = 0; k0 < p.K; k0 += 64) {
        const short* Asrc = p.A1; int kc = k0;
        if (p.A2 != nullptr && k0 >= p.k2s) { Asrc = p.A2; kc = k0 - p.k2s; }
#pragma unroll
        for (int i = 0; i < 4; ++i) {
            int chunk = wave * 4 + i;
            int row = chunk * 8 + srow;
            gload16(Asrc + (size_t)(bm + row) * p.lda + kc + scol, lA + chunk * 512);
            gload16(p.WT + (size_t)(bn + row) * p.K + k0 + scol, lB + chunk * 512);
        }
        __syncthreads();
#pragma unroll
        for (int kk = 0; kk < 2; ++kk) {
            bf16x8 af[4], bfr[4];
#pragma unroll
            for (int i = 0; i < 4; ++i) {
                int row = wr * 64 + i * 16 + q16;
                int off = (row * 128 + kk * 64 + gk * 16) ^ ((row & 7) << 4);
                af[i] = *(const bf16x8*)((const char*)lA + off);
                if (RELU) {
                    union { bf16x8 v; unsigned int w[4]; } u;
                    u.v = af[i];
#pragma unroll
                    for (int t = 0; t < 4; ++t) u.w[t] = relu_pk(u.w[t]);
                    af[i] = u.v;
                }
            }
#pragma unroll
            for (int j = 0; j < 4; ++j) {
                int row = wc * 64 + j * 16 + q16;
                int off = (row * 128 + kk * 64 + gk * 16) ^ ((row & 7) << 4);
                bfr[j] = *(const bf16x8*)((const char*)lB + off);
            }
#pragma unroll
            for (int i = 0; i < 4; ++i)
#pragma unroll
                for (int j = 0; j < 4; ++j)
                    acc[i][j] = __builtin_amdgcn_mfma_f32_16x16x32_bf16(af[i], bfr[j], acc[i][j], 0, 0, 0);
        }
        __syncthreads();
    }
    const bool sig = (p.flags & FL_SIG) != 0;
#pragma unroll
    for (int i = 0; i < 4; ++i) {
#pragma unroll
        for (int j = 0; j < 4; ++j) {
            int col = bn + wc * 64 + j * 16 + q16;
            float bv = p.bias[col];
#pragma unroll
            for (int r = 0; r < 4; ++r) {
                int row = bm + wr * 64 + i * 16 + gk * 4 + r;
                float v = acc[i][j][r] + bv;
                if (sig) v = 1.f + 1.f / (1.f + __expf(-v));
                if (p.rmask) v *= p.rmask[row];
                if (CF32) ((float*)p.C)[(size_t)row * p.ldc + col] = v;
                else      ((short*)p.C)[(size_t)row * p.ldc + col] = f2bf(v);
            }
        }
    }
}

// ---------------- batched-pair MFMA attention, per-z compile-time KT ----------------
struct AP {
    const short* q; const short* kv; const float* mask; const short* gate;
    const short* add; short* out; int Nq, Nk;
};

template<int KT>
__device__ __forceinline__ void attn_body(const AP& a, short* sK, short* sVT, float* sMask)
{
    constexpr int KT2 = (KT + 1) / 2;
    constexpr int KV = KT2 * 32;
    constexpr int VROWB = KV * 2;
    const int Nq = a.Nq, Nk = a.Nk;
    const int tid = threadIdx.x;
    const int h = blockIdx.x, b = blockIdx.y;
    const int lane = tid & 63, w = tid >> 6;
    const int g = lane >> 4, q16 = lane & 15;

    union U8 { uint4 u4; short s[8]; };

    for (int u = tid; u < Nk * 16; u += 256) {
        int k = u >> 4, seg = u & 15;
        U8 t; t.u4 = *(const uint4*)(a.kv + (size_t)(b * Nk + k) * 3072 + h * 128 + seg * 8);
        if (a.gate) {
            const short* gp = a.gate + b * 1024 + h * 128 + seg * 8;
#pragma unroll
            for (int j = 0; j < 8; ++j) {
                float gv = bf2f(gp[j]);
                t.s[j] = f2bf(bf2f(t.s[j]) * gv * gv);
            }
        }
        int off = (k * 256 + seg * 16) ^ ((k & 7) << 4);
        *(uint4*)((char*)sK + off) = t.u4;
    }
    for (int u = tid; u < Nk * 16; u += 256) {
        int k = u >> 4, seg = u & 15;
        U8 t; t.u4 = *(const uint4*)(a.kv + (size_t)(b * Nk + k) * 3072 + 2048 + h * 128 + seg * 8);
#pragma unroll
        for (int j = 0; j < 8; ++j) {
            int d = seg * 8 + j;
            int off = (d * VROWB + ((k >> 3) << 4) + (k & 7) * 2) ^ ((d & 7) << 4);
            *(short*)((char*)sVT + off) = t.s[j];
        }
    }
    for (int u = tid; u < (KV - Nk) * 128; u += 256) {
        int k = Nk + (u >> 7), d = u & 127;
        int off = (d * VROWB + ((k >> 3) << 4) + (k & 7) * 2) ^ ((d & 7) << 4);
        *(short*)((char*)sVT + off) = 0;
    }
    for (int u = tid; u < KV; u += 256)
        sMask[u] = (u < Nk) ? a.mask[b * Nk + u] : 0.f;
    __syncthreads();

    const int QT = (Nq + 15) >> 4;
    for (int qt = w; qt < QT; qt += 4) {
        int qrow = qt * 16 + q16; if (qrow >= Nq) qrow = Nq - 1;
        const short* qp = a.q + (size_t)(b * Nq + qrow) * 3072 + 1024 + h * 128 + g * 8;
        bf16x8 qf[4];
#pragma unroll
        for (int ks = 0; ks < 4; ++ks)
            qf[ks] = *(const bf16x8*)(qp + ks * 32);

        f32x4 accs[KT];
#pragma unroll
        for (int kt = 0; kt < KT; ++kt) accs[kt] = (f32x4){0.f, 0.f, 0.f, 0.f};
#pragma unroll
        for (int kt = 0; kt < KT; ++kt) {
            int krow = kt * 16 + q16;
#pragma unroll
            for (int ks = 0; ks < 4; ++ks) {
                bf16x8 kf = *(const bf16x8*)((char*)sK +
                    ((krow * 256 + ks * 64 + g * 16) ^ ((krow & 7) << 4)));
                accs[kt] = __builtin_amdgcn_mfma_f32_16x16x32_bf16(kf, qf[ks], accs[kt], 0, 0, 0);
            }
        }
        float pv[KT][4];
        float mx = -__builtin_inff();
#pragma unroll
        for (int kt = 0; kt < KT; ++kt)
#pragma unroll
            for (int r = 0; r < 4; ++r) {
                int k = kt * 16 + g * 4 + r;
                float s = (sMask[k] > 0.f) ? accs[kt][r] * SCALEF : -__builtin_inff();
                pv[kt][r] = s;
                mx = fmaxf(mx, s);
            }
        mx = fmaxf(mx, __shfl_xor(mx, 16, 64));
        mx = fmaxf(mx, __shfl_xor(mx, 32, 64));
        float sum = 0.f;
#pragma unroll
        for (int kt = 0; kt < KT; ++kt)
#pragma unroll
            for (int r = 0; r < 4; ++r) {
                float pp = __expf(pv[kt][r] - mx);
                pv[kt][r] = pp;
                sum += pp;
            }
        sum += __shfl_xor(sum, 16, 64);
        sum += __shfl_xor(sum, 32, 64);
        float rden = 1.f / sum;

        unsigned int wA[KT2 * 2], wB[KT2 * 2];
#pragma unroll
        for (int t = 0; t < KT2 * 2; ++t) {
            if (t < KT) { wA[t] = pkbf(pv[t][0], pv[t][1]); wB[t] = pkbf(pv[t][2], pv[t][3]); }
            else { wA[t] = 0u; wB[t] = 0u; }
        }
        f32x4 acco[8];
#pragma unroll
        for (int dt = 0; dt < 8; ++dt) acco[dt] = (f32x4){0.f, 0.f, 0.f, 0.f};
        const int srcA = (((g & 1) * 2) * 16 + q16) * 4;
        const int srcB = (((g & 1) * 2 + 1) * 16 + q16) * 4;
        const bool hi = g >= 2;
#pragma unroll
        for (int kt2 = 0; kt2 < KT2; ++kt2) {
            int a0_ = __builtin_amdgcn_ds_bpermute(srcA, (int)wA[2 * kt2]);
            int a1_ = __builtin_amdgcn_ds_bpermute(srcA, (int)wA[2 * kt2 + 1]);
            int b0_ = __builtin_amdgcn_ds_bpermute(srcA, (int)wB[2 * kt2]);
            int b1_ = __builtin_amdgcn_ds_bpermute(srcA, (int)wB[2 * kt2 + 1]);
            int c0_ = __builtin_amdgcn_ds_bpermute(srcB, (int)wA[2 * kt2]);
            int c1_ = __builtin_amdgcn_ds_bpermute(srcB, (int)wA[2 * kt2 + 1]);
            int d0_ = __builtin_amdgcn_ds_bpermute(srcB, (int)wB[2 * kt2]);
            int d1_ = __builtin_amdgcn_ds_bpermute(srcB, (int)wB[2 * kt2 + 1]);
            union { int wd[4]; bf16x8 v; } pf;
            pf.wd[0] = hi ? a1_ : a0_;
            pf.wd[1] = hi ? b1_ : b0_;
            pf.wd[2] = hi ? c1_ : c0_;
            pf.wd[3] = hi ? d1_ : d0_;
#pragma unroll
            for (int dt = 0; dt < 8; ++dt) {
                int drow = dt * 16 + q16;
                bf16x8 vf = *(const bf16x8*)((char*)sVT +
                    ((drow * VROWB + kt2 * 64 + g * 16) ^ ((drow & 7) << 4)));
                acco[dt] = __builtin_amdgcn_mfma_f32_16x16x32_bf16(pf.v, vf, acco[dt], 0, 0, 0);
            }
        }
        float rd[4];
#pragma unroll
        for (int r = 0; r < 4; ++r) {
            int rv = __builtin_amdgcn_ds_bpermute((g * 4 + r) * 4, __builtin_bit_cast(int, rden));
            rd[r] = __builtin_bit_cast(float, rv);
        }
#pragma unroll
        for (int dt = 0; dt < 8; ++dt)
#pragma unroll
            for (int r = 0; r < 4; ++r) {
                int q = qt * 16 + g * 4 + r;
                if (q < Nq) {
                    size_t oidx = (size_t)(b * Nq + q) * 1024 + h * 128 + dt * 16 + q16;
                    float val = acco[dt][r] * rd[r];
                    if (a.add) val += bf2f(a.add[oidx]);
                    a.out[oidx] = f2bf(val);
                }
            }
    }
}

template<int KT0, int KT1>
__global__ __launch_bounds__(256, 2) void attn2_mfma(AP a0, AP a1)
{
    __shared__ short sK[112 * 128];
    __shared__ short sVT[128 * 128];
    __shared__ float sMask[128];
    if (blockIdx.z == 0) attn_body<KT0>(a0, sK, sVT, sMask);
    else                 attn_body<KT1>(a1, sK, sVT, sMask);
}

// ---------------- fused helpers ----------------
struct TP { const float* W; short* WT; int K, N, nblk; };
struct TPack { TP t[12]; };

__global__ void transpose12_k(TPack pk) {
    __shared__ short tile[32][33];
    int bid = blockIdx.x;
    int pi = 0;
    while (bid >= pk.t[pi].nblk) { bid -= pk.t[pi].nblk; ++pi; }
    const float* W = pk.t[pi].W;
    short* WT = pk.t[pi].WT;
    int K = pk.t[pi].K, N = pk.t[pi].N;
    int nbx = N >> 5;
    int nb = (bid % nbx) * 32, kb = (bid / nbx) * 32;
    int tx = threadIdx.x & 31, ty = threadIdx.x >> 5;
    for (int i = ty; i < 32; i += 8)
        tile[i][tx] = f2bf(W[(size_t)(kb + i) * N + nb + tx]);
    __syncthreads();
    for (int i = ty; i < 32; i += 8)
        WT[(size_t)(nb + i) * K + kb + tx] = tile[tx][i];
}

__global__ void cvt2_bf(const float* __restrict__ a, short* __restrict__ oa, int na8,
                        const float* __restrict__ b, short* __restrict__ ob, int nb8) {
    int i = blockIdx.x * 256 + threadIdx.x;
    const float* src; short* dst; int loc;
    if (i < na8) { src = a; dst = oa; loc = i; }
    else if (i < na8 + nb8) { src = b; dst = ob; loc = i - na8; }
    else return;
    const float4* p = (const float4*)(src + (size_t)loc * 8);
    float4 x = p[0], y = p[1];
    uint4 val;
    val.x = pkbf(x.x, x.y); val.y = pkbf(x.z, x.w);
    val.z = pkbf(y.x, y.y); val.w = pkbf(y.z, y.w);
    *(uint4*)(dst + (size_t)loc * 8) = val;
}

__global__ void mean2_k(const short* __restrict__ Xv, const float* __restrict__ mv, short* __restrict__ ov_,
                        const short* __restrict__ Xt, const float* __restrict__ mt, short* __restrict__ ot_) {
    int idx = blockIdx.x * 256 + threadIdx.x;
    const short* X; const float* mk; short* o; int N; int loc;
    if (idx < 131072) { X = Xv; mk = mv; o = ov_; N = 100; loc = idx; }
    else { X = Xt; mk = mt; o = ot_; N = 36; loc = idx - 131072; }
    int b = loc >> 10, d = loc & 1023;
    float s = 0.f, c = 0.f;
    for (int n = 0; n < N; ++n) {
        float m = mk[b * N + n];
        s += bf2f(X[(size_t)(b * N + n) * 1024 + d]) * m;
        c += m;
    }
    o[loc] = f2bf(s / c);
}

// ---------------- orchestration ----------------
extern "C" void kernel_launch(void* const* d_in, const int* in_sizes, int n_in,
                              void* d_out, int out_size, void* d_ws, size_t ws_size,
                              hipStream_t stream)
{
    const float* v_in  = (const float*)d_in[0];
    const float* t_in  = (const float*)d_in[1];
    const float* vm    = (const float*)d_in[2];
    const float* tm    = (const float*)d_in[3];
    const float* vlin_w = (const float*)d_in[4];  const float* vlin_b = (const float*)d_in[5];
    const float* tlin_w = (const float*)d_in[6];  const float* tlin_b = (const float*)d_in[7];
    const float* iv_w  = (const float*)d_in[8];   const float* iv_b  = (const float*)d_in[9];
    const float* it_w  = (const float*)d_in[10];  const float* it_b  = (const float*)d_in[11];
    const float* ivo_w = (const float*)d_in[12];  const float* ivo_b = (const float*)d_in[13];
    const float* ito_w = (const float*)d_in[14];  const float* ito_b = (const float*)d_in[15];
    const float* gv_w  = (const float*)d_in[16];  const float* gv_b  = (const float*)d_in[17];
    const float* gt_w  = (const float*)d_in[18];  const float* gt_b  = (const float*)d_in[19];
    const float* av_w  = (const float*)d_in[20];  const float* av_b  = (const float*)d_in[21];
    const float* at_w  = (const float*)d_in[22];  const float* at_b  = (const float*)d_in[23];
    const float* avo_w = (const float*)d_in[24];  const float* avo_b = (const float*)d_in[25];
    const float* ato_w = (const float*)d_in[26];  const float* ato_b = (const float*)d_in[27];

    short* ws = (short*)d_ws;
    const size_t WTvlin = 0;
    const size_t WTtlin = 2097152;
    const size_t WTiv   = 3145728;
    const size_t WTit   = 6291456;
    const size_t WTivo  = 9437184;
    const size_t WTito  = 11534336;
    const size_t WTgv   = 13631488;
    const size_t WTgt   = 14680064;
    const size_t WTav   = 15728640;
    const size_t WTat   = 18874368;
    const size_t WTavo  = 22020096;
    const size_t WTato  = 23068672;
    const size_t V_A    = 24117248;
    const size_t V_B    = 37224448;
    const size_t T_A    = 50331648;
    const size_t T_B    = 55050240;
    const size_t VT     = 59768832;
    const size_t TT     = 99090432;
    const size_t V_UP   = 113246208;
    const size_t T_UP   = 126353408;
    const size_t VMEAN  = 131072000;
    const size_t TMEAN  = 131203072;
    const size_t GATEV  = 131334144;
    const size_t GATET  = 131465216;
    const size_t TOTAL  = 131596288;
    if (ws_size < TOTAL * 2ull) return;

    short* v_a = ws + V_A; short* v_b = ws + V_B;
    short* t_a = ws + T_A; short* t_b = ws + T_B;
    short* vt = ws + VT;   short* tt = ws + TT;
    short* v_up = ws + V_UP; short* t_up = ws + T_UP;
    short* vmean = ws + VMEAN; short* tmean = ws + TMEAN;
    short* gateV = ws + GATEV; short* gateT = ws + GATET;
    float* ov = (float*)d_out;
    float* ot = ov + 13107200;

    {
        TPack pk;
        auto set = [&](int i, const float* W, size_t off, int K, int N) {
            pk.t[i] = TP{W, ws + off, K, N, (N / 32) * (K / 32)};
        };
        set(0, vlin_w, WTvlin, 2048, 1024);  set(1, tlin_w, WTtlin, 1024, 1024);
        set(2, iv_w, WTiv, 1024, 3072);      set(3, it_w, WTit, 1024, 3072);
        set(4, ivo_w, WTivo, 2048, 1024);    set(5, ito_w, WTito, 2048, 1024);
        set(6, gv_w, WTgv, 1024, 1024);      set(7, gt_w, WTgt, 1024, 1024);
        set(8, av_w, WTav, 1024, 3072);      set(9, at_w, WTat, 1024, 3072);
        set(10, avo_w, WTavo, 1024, 1024);   set(11, ato_w, WTato, 1024, 1024);
        int total = 0;
        for (int i = 0; i < 12; ++i) total += pk.t[i].nblk;
        transpose12_k<<<total, 256, 0, stream>>>(pk);
    }

    auto GPm = [&](const short* A1, const short* A2, int k2s, int lda, size_t WToff,
                   const float* bp, const float* rm, void* Cp, int M, int N, int K, int flags) {
        return GP{A1, A2, ws + WToff, bp, rm, Cp, k2s, lda, M, N, K, N, flags};
    };
    auto APm = [&](const short* q, const short* kv, const float* mk, const short* gt,
                   const short* adds, short* o, int Nq, int Nk) {
        return AP{q, kv, mk, gt, adds, o, Nq, Nk};
    };

    {
        short* v_cv = ws + VT;
        short* t_cv = ws + TT;
        int na8 = 12800 * 2048 / 8, nb8 = 4608 * 1024 / 8;
        cvt2_bf<<<(na8 + nb8 + 255) / 256, 256, 0, stream>>>(v_in, v_cv, na8, t_in, t_cv, nb8);
        gemm2_k<0, 0><<<dim3(8, 100, 2), 256, 0, stream>>>(
            GPm(v_cv, nullptr, 0, 2048, WTvlin, vlin_b, vm, v_a, 12800, 1024, 2048, 0),
            GPm(t_cv, nullptr, 0, 1024, WTtlin, tlin_b, tm, t_a, 4608, 1024, 1024, 0));
    }

    for (int ib = 0; ib < 2; ++ib) {
        // ---- InterModalityUpdate ----
        gemm2_k<1, 0><<<dim3(24, 100, 2), 256, 0, stream>>>(
            GPm(v_a, nullptr, 0, 1024, WTiv, iv_b, nullptr, vt, 12800, 3072, 1024, 0),
            GPm(t_a, nullptr, 0, 1024, WTit, it_b, nullptr, tt, 4608, 3072, 1024, 0));
        attn2_mfma<3, 7><<<dim3(8, 128, 2), 256, 0, stream>>>(
            APm(vt, tt, tm, nullptr, nullptr, v_up, 100, 36),     // t2v (Nk=36)
            APm(tt, vt, vm, nullptr, nullptr, t_up, 36, 100));    // v2t (Nk=100)
        gemm2_k<0, 0><<<dim3(8, 100, 2), 256, 0, stream>>>(
            GPm(v_a, v_up, 1024, 1024, WTivo, ivo_b, nullptr, v_b, 12800, 1024, 2048, 0),
            GPm(t_a, t_up, 1024, 1024, WTito, ito_b, nullptr, t_b, 4608, 1024, 2048, 0));
        // ---- DyIntraModalityUpdate ----
        mean2_k<<<1024, 256, 0, stream>>>(v_b, vm, vmean, t_b, tm, tmean);
        gemm2_k<1, 0><<<dim3(8, 1, 2), 256, 0, stream>>>(
            GPm(vmean, nullptr, 0, 1024, WTgv, gv_b, nullptr, gateT, 128, 1024, 1024, FL_SIG),
            GPm(tmean, nullptr, 0, 1024, WTgt, gt_b, nullptr, gateV, 128, 1024, 1024, FL_SIG));
        gemm2_k<1, 0><<<dim3(24, 100, 2), 256, 0, stream>>>(
            GPm(v_b, nullptr, 0, 1024, WTav, av_b, vm, vt, 12800, 3072, 1024, 0),
            GPm(t_b, nullptr, 0, 1024, WTat, at_b, tm, tt, 4608, 3072, 1024, 0));
        attn2_mfma<7, 3><<<dim3(8, 128, 2), 256, 0, stream>>>(
            APm(vt, vt, vm, gateV, v_b, v_up, 100, 100),          // v2v (+residual)
            APm(tt, tt, tm, gateT, t_b, t_up, 36, 36));           // t2t (+residual)
        if (ib == 1) {
            gemm2_k<0, 1><<<dim3(8, 100, 2), 256, 0, stream>>>(
                GPm(v_up, nullptr, 0, 1024, WTavo, avo_b, nullptr, ov, 12800, 1024, 1024, 0),
                GPm(t_up, nullptr, 0, 1024, WTato, ato_b, nullptr, ot, 4608, 1024, 1024, 0));
        } else {
            gemm2_k<0, 0><<<dim3(8, 100, 2), 256, 0, stream>>>(
                GPm(v_up, nullptr, 0, 1024, WTavo, avo_b, vm, v_a, 12800, 1024, 1024, 0),
                GPm(t_up, nullptr, 0, 1024, WTato, ato_b, tm, t_a, 4608, 1024, 1024, 0));
        }
    }
}